// Round 10
// baseline (110.382 us; speedup 1.0000x reference)
//
#include <hip/hip_runtime.h>
#include <hip/hip_bf16.h>
#include <math.h>

#define B    16
#define SEQK 256
#define HID  128
#define NH   4
#define DK   32
#define DIM  64
#define OUTD 128

typedef __attribute__((ext_vector_type(8))) short short8;
typedef __attribute__((ext_vector_type(4))) float floatx4;

// setup roles: 192 proj (32 rows each) + 32 mvt + 16 wob = 240 blocks (1 round)
#define NB_PROJ 192
#define NB_MVT  32
#define NB_WOB  16
#define NB_SETUP (NB_PROJ + NB_MVT + NB_WOB)

__device__ __forceinline__ unsigned f2bf(float x) {
    union { float f; unsigned u; } v; v.f = x;
    return (v.u + 0x7FFFu + ((v.u >> 16) & 1u)) >> 16;   // RNE bf16
}

// ---------------------------------------------------------------------------
// setup: (a) Q/K projection (32 rows/block, in-LDS weight transpose),
// (b) mvt bf16 pack-transpose, (c) Wo -> bf16.
__global__ __launch_bounds__(256) void setup_kernel(
    const float* __restrict__ query, const float* __restrict__ key,
    const float* __restrict__ value, const int* __restrict__ mask,
    const float* __restrict__ Wq, const float* __restrict__ bq,
    const float* __restrict__ Wk, const float* __restrict__ bk,
    const float* __restrict__ Wo,
    float* __restrict__ qp, float* __restrict__ kp_t,
    unsigned* __restrict__ mvt_u, unsigned* __restrict__ wob_u)
{
    __shared__ float smem[32 * 128 + 32 * 130];   // in32 | Wt = 32.6 KB
    const int bid = blockIdx.x;
    const int t   = threadIdx.x;

    if (bid < NB_PROJ) {
        float* in32 = smem;            // [32][128] = 1024 float4
        float* Wt   = smem + 4096;     // [32][130]
        const int r0 = bid * 32;       // 32-row blocks never straddle q/k split
        const bool isQ = (r0 < 2048);
        const float4* src4 = (const float4*)(isQ ? (query + r0 * 128)
                                                 : (key + (r0 - 2048) * 128));
        {
            float4* in4 = (float4*)in32;
#pragma unroll
            for (int s = 0; s < 4; ++s) in4[t + 256 * s] = src4[t + 256 * s];
        }
        const float* Wsrc = isQ ? Wq : Wk;
        const int j  = t & 127;
        const int rg = (t >> 7) * 16;
        const float bias = isQ ? bq[j] : bk[j];
        float acc[16];
#pragma unroll
        for (int r = 0; r < 16; ++r) acc[r] = bias;

        for (int ic = 0; ic < 4; ++ic) {
            __syncthreads();   // in32 ready (ic=0); Wt no longer read (ic>0)
            {
                const int i4 = t & 7, jg = t >> 3;
#pragma unroll
                for (int jj = 0; jj < 4; ++jj) {
                    const int jw = jg + jj * 32;
                    const float4 w = *(const float4*)(Wsrc + jw * 128 + ic * 32 + i4 * 4);
                    Wt[(i4 * 4 + 0) * 130 + jw] = w.x;
                    Wt[(i4 * 4 + 1) * 130 + jw] = w.y;
                    Wt[(i4 * 4 + 2) * 130 + jw] = w.z;
                    Wt[(i4 * 4 + 3) * 130 + jw] = w.w;
                }
            }
            __syncthreads();
#pragma unroll 2
            for (int i4 = 0; i4 < 8; ++i4) {
                const float w0 = Wt[(i4 * 4 + 0) * 130 + j];
                const float w1 = Wt[(i4 * 4 + 1) * 130 + j];
                const float w2 = Wt[(i4 * 4 + 2) * 130 + j];
                const float w3 = Wt[(i4 * 4 + 3) * 130 + j];
#pragma unroll
                for (int r = 0; r < 16; ++r) {
                    const float4 xv = ((const float4*)in32)[(rg + r) * 32 + ic * 8 + i4];
                    acc[r] = fmaf(xv.x, w0, fmaf(xv.y, w1, fmaf(xv.z, w2, fmaf(xv.w, w3, acc[r]))));
                }
            }
        }

        if (isQ) {
            const float scale = 0.17677669529663687f;  // 1/sqrt(32) folded in
#pragma unroll
            for (int r = 0; r < 16; ++r) qp[(r0 + rg + r) * 128 + j] = acc[r] * scale;
        } else {
#pragma unroll
            for (int r = 0; r < 16; ++r) {
                const int row = r0 - 2048 + rg + r;
                const int bb = row >> 8, k = row & 255;
                kp_t[(bb * 128 + j) * 256 + k] = acc[r];
            }
        }
    } else if (bid < NB_PROJ + NB_MVT) {
        // mvt pack: bf16 transposed mvt[b][c][k]; c<64 = m?v:0, c>=64 = m?1:0
        const int bb = (bid - NB_PROJ) >> 1, kt = (bid - NB_PROJ) & 1;  // 128 k half
        const int c4 = t & 15, kp2 = t >> 4;
#pragma unroll
        for (int rr = 0; rr < 4; ++rr) {
            const int kpair = kp2 + rr * 16;               // 0..63
            const int k0 = kt * 128 + kpair * 2;
            const float4 v0 = *(const float4*)(value + (bb * 256 + k0) * 64 + c4 * 4);
            const float4 v1 = *(const float4*)(value + (bb * 256 + k0 + 1) * 64 + c4 * 4);
            const int4   m0 = *(const int4*)(mask + (bb * 256 + k0) * 64 + c4 * 4);
            const int4   m1 = *(const int4*)(mask + (bb * 256 + k0 + 1) * 64 + c4 * 4);
            const float a0[4] = {v0.x, v0.y, v0.z, v0.w};
            const float a1[4] = {v1.x, v1.y, v1.z, v1.w};
            const int   i0[4] = {m0.x, m0.y, m0.z, m0.w};
            const int   i1[4] = {m1.x, m1.y, m1.z, m1.w};
#pragma unroll
            for (int cc = 0; cc < 4; ++cc) {
                const int c = c4 * 4 + cc;
                const unsigned mv = (f2bf(i1[cc] ? a1[cc] : 0.f) << 16)
                                  |  f2bf(i0[cc] ? a0[cc] : 0.f);
                const unsigned ff = ((i1[cc] ? 0x3F80u : 0u) << 16)
                                  |  (i0[cc] ? 0x3F80u : 0u);
                mvt_u[(bb * 128 + c) * 128 + kt * 64 + kpair]      = mv;
                mvt_u[(bb * 128 + 64 + c) * 128 + kt * 64 + kpair] = ff;
            }
        }
    } else {
        // Wo fp32 -> bf16, same [o][j] layout
        const int base = (bid - NB_PROJ - NB_MVT) * 512 + t;   // 2 per thread
#pragma unroll
        for (int s = 0; s < 2; ++s) {
            const int idx4 = base + s * 256;                   // 0..8191
            const float4 w = ((const float4*)Wo)[idx4];
            uint2 p;
            p.x = (f2bf(w.y) << 16) | f2bf(w.x);
            p.y = (f2bf(w.w) << 16) | f2bf(w.z);
            ((uint2*)wob_u)[idx4] = p;
        }
    }
}

// ---------------------------------------------------------------------------
// Fused attention (R6-proven): block = (qtile8, b), wave = head. Grid 256.
__global__ __launch_bounds__(256) void attn_kernel(
    const float* __restrict__ qp, const float* __restrict__ kp_t,
    const short* __restrict__ mvt_s, const short* __restrict__ wob_s,
    const float* __restrict__ bo, float* __restrict__ out)
{
    const int qt = blockIdx.x, b = blockIdx.y;
    const int q0 = qt * 8;
    const int t = threadIdx.x, h = t >> 6, L = t & 63;

    __shared__ float qs[NH * 32 * 12];     // qs[h][i][q], stride 12
    __shared__ short es[NH * 16 * 264];    // es[h][q][k] bf16, stride 264
    __shared__ short xs[16 * 264];         // xs[q][j] bf16, stride 264

    // stage q: qs[h][i][q] = qp_scaled[b*128+q0+q][h*32+i]
    {
        const int j = t & 127, qg = t >> 7;
        const int hh = j >> 5, ii = j & 31;
#pragma unroll
        for (int e = 0; e < 4; ++e) {
            const int q = qg * 4 + e;
            qs[hh * 384 + ii * 12 + q] = qp[(b * 128 + q0 + q) * 128 + j];
        }
    }
    __syncthreads();

    // G1: scores fp32. Lane L covers k = L*4..+4 for 8 q of its head.
    float s[8][4];
#pragma unroll
    for (int q = 0; q < 8; ++q)
#pragma unroll
        for (int kk = 0; kk < 4; ++kk) s[q][kk] = 0.f;
    {
        const float* kpb = kp_t + (b * 128 + h * 32) * 256 + L * 4;
        const float* qb  = qs + h * 384;
#pragma unroll 4
        for (int i = 0; i < 32; ++i) {
            const float4 kv = *(const float4*)(kpb + i * 256);
            const float4 qa = *(const float4*)(qb + i * 12);
            const float4 qc = *(const float4*)(qb + i * 12 + 4);
            const float qv[8] = {qa.x, qa.y, qa.z, qa.w, qc.x, qc.y, qc.z, qc.w};
            const float kw[4] = {kv.x, kv.y, kv.z, kv.w};
#pragma unroll
            for (int q = 0; q < 8; ++q)
#pragma unroll
                for (int kk = 0; kk < 4; ++kk)
                    s[q][kk] = fmaf(qv[q], kw[kk], s[q][kk]);
        }
    }

    // softmax per q: wave-wide max, exp, bf16 -> es (MFMA A-frag layout)
#pragma unroll
    for (int q = 0; q < 8; ++q) {
        float m = fmaxf(fmaxf(s[q][0], s[q][1]), fmaxf(s[q][2], s[q][3]));
#pragma unroll
        for (int off = 32; off > 0; off >>= 1) m = fmaxf(m, __shfl_xor(m, off, 64));
        const unsigned e01 = (f2bf(__expf(s[q][1] - m)) << 16) | f2bf(__expf(s[q][0] - m));
        const unsigned e23 = (f2bf(__expf(s[q][3] - m)) << 16) | f2bf(__expf(s[q][2] - m));
        *(uint2*)&es[h * 4224 + q * 264 + L * 4] = make_uint2(e01, e23);
    }
    // no barrier: es produced and consumed by the same wave

    // G2: PV via MFMA. D tiles 0..3 = num, 4..7 = den.
    const int lq = L & 15, lk = (L >> 4) * 8;
    floatx4 pv[8];
#pragma unroll
    for (int tt = 0; tt < 8; ++tt) pv[tt] = (floatx4){0.f, 0.f, 0.f, 0.f};
    {
        const short* eb = es + h * 4224 + lq * 264;
        const short* mb = mvt_s + (b * 128) * 256 + lk;
#pragma unroll
        for (int c8 = 0; c8 < 8; ++c8) {
            const short8 a = *(const short8*)(eb + c8 * 32 + lk);
#pragma unroll
            for (int tt = 0; tt < 8; ++tt) {
                const short8 bf = *(const short8*)(mb + (tt * 16 + lq) * 256 + c8 * 32);
                pv[tt] = __builtin_amdgcn_mfma_f32_16x16x32_bf16(a, bf, pv[tt], 0, 0, 0);
            }
        }
    }
    // x = num/den -> xs[q][h*64+c] bf16 (rows 0..7 meaningful)
    if ((L >> 4) < 2) {
#pragma unroll
        for (int tt = 0; tt < 4; ++tt)
#pragma unroll
            for (int r = 0; r < 4; ++r) {
                const int row = (L >> 4) * 4 + r;
                xs[row * 264 + h * 64 + tt * 16 + lq] =
                    (short)f2bf(pv[tt][r] / pv[tt + 4][r]);
            }
    }
    __syncthreads();

    // G3: O-projection via MFMA, full K=256 -> direct store (no atomics)
    floatx4 oa[2];
    oa[0] = (floatx4){0.f, 0.f, 0.f, 0.f};
    oa[1] = (floatx4){0.f, 0.f, 0.f, 0.f};
    {
        const short* xb = xs + lq * 264;
#pragma unroll
        for (int j8 = 0; j8 < 8; ++j8) {
            const short8 a = *(const short8*)(xb + j8 * 32 + lk);
#pragma unroll
            for (int w = 0; w < 2; ++w) {
                const int o = (h * 2 + w) * 16 + lq;
                const short8 bf = *(const short8*)(wob_s + o * 256 + j8 * 32 + lk);
                oa[w] = __builtin_amdgcn_mfma_f32_16x16x32_bf16(a, bf, oa[w], 0, 0, 0);
            }
        }
    }
    if ((L >> 4) < 2) {
#pragma unroll
        for (int w = 0; w < 2; ++w) {
            const int o = (h * 2 + w) * 16 + lq;
            const float bov = bo[o];
#pragma unroll
            for (int r = 0; r < 4; ++r) {
                const int row = (L >> 4) * 4 + r;
                out[(b * 128 + q0 + row) * 128 + o] = oa[w][r] + bov;
            }
        }
    }
}

extern "C" void kernel_launch(void* const* d_in, const int* in_sizes, int n_in,
                              void* d_out, int out_size, void* d_ws, size_t ws_size,
                              hipStream_t stream)
{
    const float* query = (const float*)d_in[0];
    const float* key   = (const float*)d_in[1];
    const float* value = (const float*)d_in[2];
    const int*   mask  = (const int*)d_in[3];
    const float* Wq    = (const float*)d_in[4];
    const float* bq    = (const float*)d_in[5];
    const float* Wk    = (const float*)d_in[6];
    const float* bk    = (const float*)d_in[7];
    const float* Wo    = (const float*)d_in[8];
    const float* bo    = (const float*)d_in[9];
    float* out = (float*)d_out;

    float* ws       = (float*)d_ws;
    float* qp       = ws;                           // 262144 f32
    float* kp_t     = qp + 262144;                  // 524288 f32
    unsigned* mvt_u = (unsigned*)(kp_t + 524288);   // 262144 u32
    unsigned* wob_u = mvt_u + 262144;               // 16384 u32

    setup_kernel<<<NB_SETUP, 256, 0, stream>>>(query, key, value, mask,
                                               Wq, bq, Wk, bk, Wo,
                                               qp, kp_t, mvt_u, wob_u);
    attn_kernel<<<dim3(16, B), 256, 0, stream>>>(qp, kp_t,
                                                 (const short*)mvt_u,
                                                 (const short*)wob_u, bo, out);
}

// Round 11
// 101.413 us; speedup vs baseline: 1.0884x; 1.0884x over previous
//
#include <hip/hip_runtime.h>
#include <hip/hip_bf16.h>
#include <math.h>

#define B    16
#define SEQK 256
#define HID  128
#define NH   4
#define DK   32
#define DIM  64
#define OUTD 128

typedef __attribute__((ext_vector_type(8))) short short8;
typedef __attribute__((ext_vector_type(4))) float floatx4;

// setup roles (R6-measured-best): 384 proj (16 rows) + 64 mvt + 32 wob
#define NB_PROJ 384
#define NB_MVT  64
#define NB_WOB  32
#define NB_SETUP (NB_PROJ + NB_MVT + NB_WOB)

__device__ __forceinline__ unsigned f2bf(float x) {
    union { float f; unsigned u; } v; v.f = x;
    return (v.u + 0x7FFFu + ((v.u >> 16) & 1u)) >> 16;   // RNE bf16
}

// ---------------------------------------------------------------------------
// setup (R6-proven): (a) Q/K projection with in-LDS weight transpose,
// (b) mvt bf16 pack-transpose, (c) Wo -> bf16.
__global__ __launch_bounds__(256) void setup_kernel(
    const float* __restrict__ query, const float* __restrict__ key,
    const float* __restrict__ value, const int* __restrict__ mask,
    const float* __restrict__ Wq, const float* __restrict__ bq,
    const float* __restrict__ Wk, const float* __restrict__ bk,
    const float* __restrict__ Wo,
    float* __restrict__ qp, float* __restrict__ kp_t,
    unsigned* __restrict__ mvt_u, unsigned* __restrict__ wob_u)
{
    __shared__ float smem[16 * 128 + 32 * 130];
    const int bid = blockIdx.x;
    const int t   = threadIdx.x;

    if (bid < NB_PROJ) {
        float* in16 = smem;
        float* Wt   = smem + 2048;
        const int r0 = bid * 16;
        const bool isQ = (r0 < 2048);
        const float4* src4 = (const float4*)(isQ ? (query + r0 * 128)
                                                 : (key + (r0 - 2048) * 128));
        {
            float4* in4 = (float4*)in16;
            in4[t]       = src4[t];
            in4[t + 256] = src4[t + 256];
        }
        const float* Wsrc = isQ ? Wq : Wk;
        const int j  = t & 127;
        const int rg = (t >> 7) * 8;
        const float bias = isQ ? bq[j] : bk[j];
        float acc[8];
#pragma unroll
        for (int r = 0; r < 8; ++r) acc[r] = bias;

        for (int ic = 0; ic < 4; ++ic) {
            __syncthreads();
            {
                const int i4 = t & 7, jg = t >> 3;
#pragma unroll
                for (int jj = 0; jj < 4; ++jj) {
                    const int jw = jg + jj * 32;
                    const float4 w = *(const float4*)(Wsrc + jw * 128 + ic * 32 + i4 * 4);
                    Wt[(i4 * 4 + 0) * 130 + jw] = w.x;
                    Wt[(i4 * 4 + 1) * 130 + jw] = w.y;
                    Wt[(i4 * 4 + 2) * 130 + jw] = w.z;
                    Wt[(i4 * 4 + 3) * 130 + jw] = w.w;
                }
            }
            __syncthreads();
#pragma unroll 2
            for (int i4 = 0; i4 < 8; ++i4) {
                const float w0 = Wt[(i4 * 4 + 0) * 130 + j];
                const float w1 = Wt[(i4 * 4 + 1) * 130 + j];
                const float w2 = Wt[(i4 * 4 + 2) * 130 + j];
                const float w3 = Wt[(i4 * 4 + 3) * 130 + j];
#pragma unroll
                for (int r = 0; r < 8; ++r) {
                    const float4 xv = ((const float4*)(in16 + (rg + r) * 128))[ic * 8 + i4];
                    acc[r] = fmaf(xv.x, w0, fmaf(xv.y, w1, fmaf(xv.z, w2, fmaf(xv.w, w3, acc[r]))));
                }
            }
        }

        if (isQ) {
            const float scale = 0.17677669529663687f;  // 1/sqrt(32) folded in
#pragma unroll
            for (int r = 0; r < 8; ++r) qp[(r0 + rg + r) * 128 + j] = acc[r] * scale;
        } else {
#pragma unroll
            for (int r = 0; r < 8; ++r) {
                const int row = r0 - 2048 + rg + r;
                const int bb = row >> 8, k = row & 255;
                kp_t[(bb * 128 + j) * 256 + k] = acc[r];
            }
        }
    } else if (bid < NB_PROJ + NB_MVT) {
        // mvt pack: bf16 transposed mvt[b][c][k]; c<64 = m?v:0, c>=64 = m?1:0
        const int bb = (bid - NB_PROJ) >> 2, kt = (bid - NB_PROJ) & 3;
        const int c4 = t & 15, kp2 = t >> 4;
#pragma unroll
        for (int rr = 0; rr < 2; ++rr) {
            const int kpair = kp2 + rr * 16;
            const int k0 = kt * 64 + kpair * 2;
            const float4 v0 = *(const float4*)(value + (bb * 256 + k0) * 64 + c4 * 4);
            const float4 v1 = *(const float4*)(value + (bb * 256 + k0 + 1) * 64 + c4 * 4);
            const int4   m0 = *(const int4*)(mask + (bb * 256 + k0) * 64 + c4 * 4);
            const int4   m1 = *(const int4*)(mask + (bb * 256 + k0 + 1) * 64 + c4 * 4);
            const float a0[4] = {v0.x, v0.y, v0.z, v0.w};
            const float a1[4] = {v1.x, v1.y, v1.z, v1.w};
            const int   i0[4] = {m0.x, m0.y, m0.z, m0.w};
            const int   i1[4] = {m1.x, m1.y, m1.z, m1.w};
#pragma unroll
            for (int cc = 0; cc < 4; ++cc) {
                const int c = c4 * 4 + cc;
                const unsigned mv = (f2bf(i1[cc] ? a1[cc] : 0.f) << 16)
                                  |  f2bf(i0[cc] ? a0[cc] : 0.f);
                const unsigned ff = ((i1[cc] ? 0x3F80u : 0u) << 16)
                                  |  (i0[cc] ? 0x3F80u : 0u);
                mvt_u[(bb * 128 + c) * 128 + kt * 32 + kpair]      = mv;
                mvt_u[(bb * 128 + 64 + c) * 128 + kt * 32 + kpair] = ff;
            }
        }
    } else {
        // Wo fp32 -> bf16, same [o][j] layout
        const int idx4 = (bid - NB_PROJ - NB_MVT) * 256 + t;   // 0..8191
        const float4 w = ((const float4*)Wo)[idx4];
        uint2 p;
        p.x = (f2bf(w.y) << 16) | f2bf(w.x);
        p.y = (f2bf(w.w) << 16) | f2bf(w.z);
        ((uint2*)wob_u)[idx4] = p;
    }
}

// ---------------------------------------------------------------------------
// Fused attention (R6-proven + cold-miss register prefetches).
// Block = (qtile8, b), wave = head. Grid 256.
__global__ __launch_bounds__(256) void attn_kernel(
    const float* __restrict__ qp, const float* __restrict__ kp_t,
    const short* __restrict__ mvt_s, const short* __restrict__ wob_s,
    const float* __restrict__ bo, float* __restrict__ out)
{
    const int qt = blockIdx.x, b = blockIdx.y;
    const int q0 = qt * 8;
    const int t = threadIdx.x, h = t >> 6, L = t & 63;
    const int lq = L & 15, lk = (L >> 4) * 8;

    __shared__ float qs[NH * 32 * 12];     // qs[h][i][q], stride 12
    __shared__ short es[NH * 16 * 264];    // es[h][q][k] bf16, stride 264
    __shared__ short xs[16 * 264];         // xs[q][j] bf16, stride 264

    // --- prefetch #1: G2's first-K-chunk B-frags (independent of all LDS).
    // Hides their cold L2/L3 miss under q-staging + G1.
    const short* mb = mvt_s + (b * 128) * 256 + lk;
    short8 mpf[8];
#pragma unroll
    for (int tt = 0; tt < 8; ++tt)
        mpf[tt] = *(const short8*)(mb + (tt * 16 + lq) * 256);

    // stage q: qs[h][i][q] = qp_scaled[b*128+q0+q][h*32+i]
    {
        const int j = t & 127, qg = t >> 7;
        const int hh = j >> 5, ii = j & 31;
#pragma unroll
        for (int e = 0; e < 4; ++e) {
            const int q = qg * 4 + e;
            qs[hh * 384 + ii * 12 + q] = qp[(b * 128 + q0 + q) * 128 + j];
        }
    }
    __syncthreads();

    // G1: scores fp32. Lane L covers k = L*4..+4 for 8 q of its head.
    float s[8][4];
#pragma unroll
    for (int q = 0; q < 8; ++q)
#pragma unroll
        for (int kk = 0; kk < 4; ++kk) s[q][kk] = 0.f;
    {
        const float* kpb = kp_t + (b * 128 + h * 32) * 256 + L * 4;
        const float* qb  = qs + h * 384;
#pragma unroll 4
        for (int i = 0; i < 32; ++i) {
            const float4 kv = *(const float4*)(kpb + i * 256);
            const float4 qa = *(const float4*)(qb + i * 12);
            const float4 qc = *(const float4*)(qb + i * 12 + 4);
            const float qv[8] = {qa.x, qa.y, qa.z, qa.w, qc.x, qc.y, qc.z, qc.w};
            const float kw[4] = {kv.x, kv.y, kv.z, kv.w};
#pragma unroll
            for (int q = 0; q < 8; ++q)
#pragma unroll
                for (int kk = 0; kk < 4; ++kk)
                    s[q][kk] = fmaf(qv[q], kw[kk], s[q][kk]);
        }
    }

    // softmax per q: wave-wide max, exp, bf16 -> es (MFMA A-frag layout)
#pragma unroll
    for (int q = 0; q < 8; ++q) {
        float m = fmaxf(fmaxf(s[q][0], s[q][1]), fmaxf(s[q][2], s[q][3]));
#pragma unroll
        for (int off = 32; off > 0; off >>= 1) m = fmaxf(m, __shfl_xor(m, off, 64));
        const unsigned e01 = (f2bf(__expf(s[q][1] - m)) << 16) | f2bf(__expf(s[q][0] - m));
        const unsigned e23 = (f2bf(__expf(s[q][3] - m)) << 16) | f2bf(__expf(s[q][2] - m));
        *(uint2*)&es[h * 4224 + q * 264 + L * 4] = make_uint2(e01, e23);
    }
    // no barrier: es produced and consumed by the same wave

    // --- prefetch #2: G3's wob B-frags (address-known; latency hides under
    // G2's 64 MFMAs instead of being exposed after the barrier).
    short8 wpf[2][8];
#pragma unroll
    for (int j8 = 0; j8 < 8; ++j8)
#pragma unroll
        for (int w = 0; w < 2; ++w)
            wpf[w][j8] = *(const short8*)(wob_s + ((h * 2 + w) * 16 + lq) * 256
                                          + j8 * 32 + lk);

    // G2: PV via MFMA. D tiles 0..3 = num, 4..7 = den.
    floatx4 pv[8];
#pragma unroll
    for (int tt = 0; tt < 8; ++tt) pv[tt] = (floatx4){0.f, 0.f, 0.f, 0.f};
    {
        const short* eb = es + h * 4224 + lq * 264;
#pragma unroll
        for (int c8 = 0; c8 < 8; ++c8) {
            const short8 a = *(const short8*)(eb + c8 * 32 + lk);
#pragma unroll
            for (int tt = 0; tt < 8; ++tt) {
                const short8 bf = (c8 == 0) ? mpf[tt]
                    : *(const short8*)(mb + (tt * 16 + lq) * 256 + c8 * 32);
                pv[tt] = __builtin_amdgcn_mfma_f32_16x16x32_bf16(a, bf, pv[tt], 0, 0, 0);
            }
        }
    }
    // x = num/den -> xs[q][h*64+c] bf16 (rows 0..7 meaningful)
    if ((L >> 4) < 2) {
#pragma unroll
        for (int tt = 0; tt < 4; ++tt)
#pragma unroll
            for (int r = 0; r < 4; ++r) {
                const int row = (L >> 4) * 4 + r;
                xs[row * 264 + h * 64 + tt * 16 + lq] =
                    (short)f2bf(pv[tt][r] / pv[tt + 4][r]);
            }
    }
    __syncthreads();

    // G3: O-projection via MFMA, full K=256 -> direct store (no atomics)
    floatx4 oa[2];
    oa[0] = (floatx4){0.f, 0.f, 0.f, 0.f};
    oa[1] = (floatx4){0.f, 0.f, 0.f, 0.f};
    {
        const short* xb = xs + lq * 264;
#pragma unroll
        for (int j8 = 0; j8 < 8; ++j8) {
            const short8 a = *(const short8*)(xb + j8 * 32 + lk);
#pragma unroll
            for (int w = 0; w < 2; ++w)
                oa[w] = __builtin_amdgcn_mfma_f32_16x16x32_bf16(a, wpf[w][j8], oa[w], 0, 0, 0);
        }
    }
    if ((L >> 4) < 2) {
#pragma unroll
        for (int w = 0; w < 2; ++w) {
            const int o = (h * 2 + w) * 16 + lq;
            const float bov = bo[o];
#pragma unroll
            for (int r = 0; r < 4; ++r) {
                const int row = (L >> 4) * 4 + r;
                out[(b * 128 + q0 + row) * 128 + o] = oa[w][r] + bov;
            }
        }
    }
}

extern "C" void kernel_launch(void* const* d_in, const int* in_sizes, int n_in,
                              void* d_out, int out_size, void* d_ws, size_t ws_size,
                              hipStream_t stream)
{
    const float* query = (const float*)d_in[0];
    const float* key   = (const float*)d_in[1];
    const float* value = (const float*)d_in[2];
    const int*   mask  = (const int*)d_in[3];
    const float* Wq    = (const float*)d_in[4];
    const float* bq    = (const float*)d_in[5];
    const float* Wk    = (const float*)d_in[6];
    const float* bk    = (const float*)d_in[7];
    const float* Wo    = (const float*)d_in[8];
    const float* bo    = (const float*)d_in[9];
    float* out = (float*)d_out;

    float* ws       = (float*)d_ws;
    float* qp       = ws;                           // 262144 f32
    float* kp_t     = qp + 262144;                  // 524288 f32
    unsigned* mvt_u = (unsigned*)(kp_t + 524288);   // 262144 u32
    unsigned* wob_u = mvt_u + 262144;               // 16384 u32

    setup_kernel<<<NB_SETUP, 256, 0, stream>>>(query, key, value, mask,
                                               Wq, bq, Wk, bk, Wo,
                                               qp, kp_t, mvt_u, wob_u);
    attn_kernel<<<dim3(16, B), 256, 0, stream>>>(qp, kp_t,
                                                 (const short*)mvt_u,
                                                 (const short*)wob_u, bo, out);
}